// Round 16
// baseline (238.286 us; speedup 1.0000x reference)
//
#include <hip/hip_runtime.h>
#include <hip/hip_bf16.h>

#define NGRAPH 2048
#define NNODES 64
#define HD 128
#define NEDGE 512
#define OSTRIDE 2017

using bf16x8 = __attribute__((ext_vector_type(8))) __bf16;
using f32x4  = __attribute__((ext_vector_type(4))) float;
using u32x4  = __attribute__((ext_vector_type(4))) unsigned int;

// XOR swizzle for [64][128] bf16 tiles (256-B rows).
__device__ __forceinline__ int swz(int row, int cb){ return (row<<8) + (cb ^ ((row&7)<<4)); }

__device__ __forceinline__ unsigned short bf16r(float x){
  unsigned u = __float_as_uint(x);
  return (unsigned short)((u + 0x7fffu + ((u>>16)&1u)) >> 16);  // RNE (prep only)
}
// native cast: compiler emits the hw cvt on gfx950 (R15-validated)
__device__ __forceinline__ unsigned short bf16c(float x){
  return __builtin_bit_cast(unsigned short, (__bf16)x);
}
__device__ __forceinline__ unsigned pack2c(float a, float b){
  return (unsigned)bf16c(a) | ((unsigned)bf16c(b) << 16);
}
__device__ __forceinline__ void unpack8(u32x4 u, float* f){
#pragma unroll
  for (int i=0;i<4;++i){
    unsigned w = u[i];
    f[2*i]   = __uint_as_float(w << 16);
    f[2*i+1] = __uint_as_float(w & 0xffff0000u);
  }
}
__device__ __forceinline__ bf16x8 asbf8(u32x4 u){ return __builtin_bit_cast(bf16x8, u); }
#define MFMA __builtin_amdgcn_mfma_f32_16x16x32_bf16

// ---- prep: PLAIN transposed bf16 [l][n][k] slabs; Wc = W2@pW1 merged; emb bf16;
// bc f32; eW1^T; triu table. (identical to R15)
// ws (bf16 elems): w1 @0 (3x16384), wc @49152, pw2 @98304, emb @147456 (8192),
// bc f32[3][128] @155648 (768 slots), eW1T @156416 (16384), triuTab u32[2016] @172800.
__global__ void prep_wts(const float* __restrict__ g1, const float* __restrict__ g2,
                         const float* __restrict__ p1, const float* __restrict__ p2,
                         const float* __restrict__ b2, const float* __restrict__ pb1,
                         const float* __restrict__ emb, const float* __restrict__ eW1,
                         unsigned short* __restrict__ ws)
{
  int idx = blockIdx.x*256 + threadIdx.x;
  if (idx < 49152){            // W1^T plain
    int l = idx/16384, r = idx%16384, n = r>>7, k = r&127;
    ws[idx] = bf16r(g1[l*16384 + k*128 + n]);
  } else if (idx < 98304){     // Wc^T plain, Wc = W2 @ pW1 (f32 accumulate)
    int q = idx - 49152;
    int l = q/16384, r = q%16384, n = r>>7, k = r&127;
    const float* W2 = g2 + l*16384;
    const float* P1 = p1 + l*16384;
    float s = 0.f;
    for (int mm=0; mm<128; ++mm) s = fmaf(W2[k*128+mm], P1[mm*128+n], s);
    ws[idx] = bf16r(s);
  } else if (idx < 147456){    // pW2^T plain
    int q = idx - 98304;
    int l = q/16384, r = q%16384, n = r>>7, k = r&127;
    ws[idx] = bf16r(p2[l*16384 + k*128 + n]);
  } else if (idx < 155648){    // emb bf16
    ws[idx] = bf16r(emb[idx - 147456]);
  } else if (idx < 156032){    // bc[l][n] = b2[l]@pW1[l][:,n] + pb1[l][n]  (f32)
    int q = idx - 155648, l = q/128, n = q%128;
    const float* P1 = p1 + l*16384;
    const float* B2 = b2 + l*128;
    float s = pb1[l*128 + n];
    for (int mm=0; mm<128; ++mm) s = fmaf(B2[mm], P1[mm*128+n], s);
    ((float*)(ws + 155648))[q] = s;
  } else if (idx >= 156416 && idx < 172800){   // eW1^T bf16 [n][k]
    int q = idx - 156416, n = q>>7, k = q&127;
    ws[idx] = bf16r(eW1[k*128 + n]);
  } else if (idx >= 172800 && idx < 174816){   // triu (i,j) table
    int p = idx - 172800;
    float fi = (127.0f - sqrtf((float)(16129 - 8*p))) * 0.5f;
    int i = (int)fi;
    if (i > 62) i = 62;
    if (i < 0)  i = 0;
    while ((i+1)*(127-(i+1))/2 <= p) ++i;
    while (i*(127-i)/2 > p) --i;
    int j = i + 1 + (p - i*(127-i)/2);
    ((unsigned*)(ws + 172800))[p] = ((unsigned)i << 16) | (unsigned)j;
  }
}

// Direct-from-global weight frags (L2-hot), 256-thr: wave w owns cols {w*16+lr, 64+w*16+lr}.
__device__ __forceinline__ void ldwg(const unsigned short* wt, int t, u32x4* wf){
  const int l = t & 63, w = t >> 6, lr = l & 15, lk = l >> 4;
  const unsigned char* wb = (const unsigned char*)wt;
  int n0 = w*16 + lr, n1 = 64 + n0;
#pragma unroll
  for (int ks=0; ks<4; ++ks){
    int off = ks*64 + lk*16;
    wf[ks]   = *(const u32x4*)(wb + (n0<<8) + off);
    wf[4+ks] = *(const u32x4*)(wb + (n1<<8) + off);
  }
}

// y = x @ W, written TRANSPOSED (yT [feat][node], 128-B swz rows). 256-thr (R8 map).
__device__ __forceinline__ void gemm_yT(const unsigned char* xs, const u32x4* wf,
                                        unsigned char* yT, int t)
{
  const int l = t & 63, w = t >> 6, lr = l & 15, lk = l >> 4;
  f32x4 acc[4][2] = {};
#pragma unroll
  for (int ks=0; ks<4; ++ks){
    int kByte = ks*64 + lk*16;
#pragma unroll
    for (int rt=0; rt<4; ++rt){
      bf16x8 af = asbf8(*(const u32x4*)(xs + swz(rt*16 + lr, kByte)));
      acc[rt][0] = MFMA(af, asbf8(wf[ks]),   acc[rt][0], 0,0,0);
      acc[rt][1] = MFMA(af, asbf8(wf[4+ks]), acc[rt][1], 0,0,0);
    }
  }
#pragma unroll
  for (int rt=0; rt<4; ++rt){
#pragma unroll
    for (int h=0; h<2; ++h){
      int n = h*64 + w*16 + lr;                 // output col = yT row
      unsigned w0 = pack2c(acc[rt][h][0], acc[rt][h][1]);
      unsigned w1 = pack2c(acc[rt][h][2], acc[rt][h][3]);
      int cb = (rt*32 + lk*8) ^ ((n&7)<<4);
      *(unsigned long long*)(yT + (n<<7) + cb) = ((unsigned long long)w1 << 32) | w0;
    }
  }
}

// Ping-pong 64x128 = in @ W + bias, optional relu. No internal barrier. 256-thr.
template<int RELU>
__device__ __forceinline__ void gemm_pp(const unsigned char* in, unsigned char* outb,
                                        const u32x4* wf, const float* __restrict__ bias, int t)
{
  const int l = t & 63, w = t >> 6, lr = l & 15, lk = l >> 4;
  f32x4 acc[4][2] = {};
#pragma unroll
  for (int ks=0; ks<4; ++ks){
    int kByte = ks*64 + lk*16;
#pragma unroll
    for (int rt=0; rt<4; ++rt){
      bf16x8 af = asbf8(*(const u32x4*)(in + swz(rt*16 + lr, kByte)));
      acc[rt][0] = MFMA(af, asbf8(wf[ks]),   acc[rt][0], 0,0,0);
      acc[rt][1] = MFMA(af, asbf8(wf[4+ks]), acc[rt][1], 0,0,0);
    }
  }
  int c0 = w*16 + lr, c1 = 64 + c0;
  float b0 = bias[c0], b1 = bias[c1];
  int cb0 = c0*2, cb1 = c1*2;
#pragma unroll
  for (int rt=0; rt<4; ++rt){
#pragma unroll
    for (int r=0; r<4; ++r){
      int row = rt*16 + lk*4 + r;
      float v0 = acc[rt][0][r] + b0;
      float v1 = acc[rt][1][r] + b1;
      if (RELU){ v0 = fmaxf(v0, 0.f); v1 = fmaxf(v1, 0.f); }
      *(unsigned short*)(outb + swz(row, cb0)) = bf16c(v0);
      *(unsigned short*)(outb + swz(row, cb1)) = bf16c(v1);
    }
  }
}

// h = A' @ y + bias (A' in sA_; y as yT rows in yTt). Out-of-place -> outb. 256-thr (R8 map).
__device__ __forceinline__ void gemm_aggA(const unsigned char* sA_, const unsigned char* yTt,
                                          unsigned char* outb, const float* __restrict__ bias, int t)
{
  const int l = t & 63, w = t >> 6, lr = l & 15, lk = l >> 4;
  f32x4 acc[4][2] = {};
#pragma unroll
  for (int ks=0; ks<2; ++ks){
    int kB = ks*64 + lk*16;
    bf16x8 bfr[2];
#pragma unroll
    for (int ft=0; ft<2; ++ft){
      int n = w*32 + ft*16 + lr;                // feat = yT row
      bfr[ft] = asbf8(*(const u32x4*)(yTt + (n<<7) + (kB ^ ((n&7)<<4))));
    }
#pragma unroll
    for (int rt=0; rt<4; ++rt){
      int m = rt*16 + lr;
      bf16x8 af = asbf8(*(const u32x4*)(sA_ + (m<<7) + (kB ^ ((m&7)<<4))));
      acc[rt][0] = MFMA(af, bfr[0], acc[rt][0], 0,0,0);
      acc[rt][1] = MFMA(af, bfr[1], acc[rt][1], 0,0,0);
    }
  }
  float b0 = bias[w*32 + lr], b1 = bias[w*32 + 16 + lr];
  int cb0 = (w*32 + lr)*2, cb1 = (w*32 + 16 + lr)*2;
#pragma unroll
  for (int rt=0; rt<4; ++rt){
#pragma unroll
    for (int r=0; r<4; ++r){
      int row = rt*16 + lk*4 + r;
      *(unsigned short*)(outb + swz(row, cb0)) = bf16c(acc[rt][0][r] + b0);
      *(unsigned short*)(outb + swz(row, cb1)) = bf16c(acc[rt][1][r] + b1);
    }
  }
}

// LayerNorm rows, 256-thr (row t>>2, quarter t&3), out-of-place, optional relu.
template<int RELU>
__device__ __forceinline__ void ln_rows(const unsigned char* inb,
                                        const float* __restrict__ g, const float* __restrict__ bb,
                                        unsigned char* outb, int t)
{
  int r = t >> 2, q = t & 3;
  int cb0 = q*64, c0 = q*32;
  float v[32];
#pragma unroll
  for (int i=0;i<4;++i){ u32x4 u = *(const u32x4*)(inb + swz(r, cb0 + i*16)); unpack8(u, v + i*8); }
  float s=0.f, s2=0.f;
#pragma unroll
  for (int i=0;i<32;++i){ s += v[i]; s2 += v[i]*v[i]; }
  s += __shfl_xor(s, 1); s2 += __shfl_xor(s2, 1);
  s += __shfl_xor(s, 2); s2 += __shfl_xor(s2, 2);
  float mu  = s * (1.f/128.f);
  float var = s2 * (1.f/128.f) - mu*mu;
  float rs  = rsqrtf(var + 1e-5f);
#pragma unroll
  for (int i=0;i<8;++i){
    f32x4 gv = *(const f32x4*)(g + c0 + i*4);
    f32x4 bv = *(const f32x4*)(bb + c0 + i*4);
#pragma unroll
    for (int j=0;j<4;++j){
      float val = (v[i*4+j]-mu)*rs*gv[j] + bv[j];
      if (RELU) val = fmaxf(val, 0.f);
      v[i*4+j] = val;
    }
  }
#pragma unroll
  for (int i=0;i<4;++i){
    u32x4 u;
#pragma unroll
    for (int j=0;j<4;++j) u[j] = pack2c(v[i*8+2*j], v[i*8+2*j+1]);
    *(u32x4*)(outb + swz(r, cb0 + i*16)) = u;
  }
}

// Layer-end LN: x = LN(h [+ xreg]) -> outb AND xreg (quarter-row = 4 u32x4 in regs).
template<int RESID>
__device__ __forceinline__ void ln_resid(const unsigned char* inb, u32x4* xr,
                                         const float* __restrict__ g, const float* __restrict__ bb,
                                         unsigned char* outb, int t)
{
  int r = t >> 2, q = t & 3;
  int cb0 = q*64, c0 = q*32;
  float v[32];
#pragma unroll
  for (int i=0;i<4;++i){ u32x4 u = *(const u32x4*)(inb + swz(r, cb0 + i*16)); unpack8(u, v + i*8); }
  if constexpr (RESID){
    float x[32];
#pragma unroll
    for (int i=0;i<4;++i) unpack8(xr[i], x + i*8);
#pragma unroll
    for (int j=0;j<32;++j) v[j] += x[j];
  }
  float s=0.f, s2=0.f;
#pragma unroll
  for (int i=0;i<32;++i){ s += v[i]; s2 += v[i]*v[i]; }
  s += __shfl_xor(s, 1); s2 += __shfl_xor(s2, 1);
  s += __shfl_xor(s, 2); s2 += __shfl_xor(s2, 2);
  float mu  = s * (1.f/128.f);
  float var = s2 * (1.f/128.f) - mu*mu;
  float rs  = rsqrtf(var + 1e-5f);
#pragma unroll
  for (int i=0;i<8;++i){
    f32x4 gv = *(const f32x4*)(g + c0 + i*4);
    f32x4 bv = *(const f32x4*)(bb + c0 + i*4);
#pragma unroll
    for (int j=0;j<4;++j) v[i*4+j] = (v[i*4+j]-mu)*rs*gv[j] + bv[j];
  }
#pragma unroll
  for (int i=0;i<4;++i){
    u32x4 u;
#pragma unroll
    for (int j=0;j<4;++j) u[j] = pack2c(v[i*8+2*j], v[i*8+2*j+1]);
    *(u32x4*)(outb + swz(r, cb0 + i*16)) = u;
    xr[i] = u;
  }
}

// Build A' = A+I bf16 [64][64] swizzled from int counts. 256-thr (R8 map).
__device__ __forceinline__ void buildA(const unsigned char* cntb, unsigned char* sA_, int t){
  const int* cnts = (const int*)cntb;
  int n = t >> 2, c0 = (t & 3) * 16;
  float cv[16];
#pragma unroll
  for (int j=0;j<16;++j){
    int v = cnts[n*64 + c0 + j];
    if (c0 + j == n) v += 1;
    cv[j] = (float)v;
  }
  u32x4 u0, u1;
#pragma unroll
  for (int j=0;j<4;++j){
    u0[j] = pack2c(cv[2*j],   cv[2*j+1]);
    u1[j] = pack2c(cv[8+2*j], cv[9+2*j]);
  }
  *(u32x4*)(sA_ + (n<<7) + ((c0*2)      ^ ((n&7)<<4))) = u0;
  *(u32x4*)(sA_ + (n<<7) + ((c0*2 + 16) ^ ((n&7)<<4))) = u1;
}

__global__ __launch_bounds__(256, 2) void gnn_fused(
    const int* __restrict__ nf, const int* __restrict__ ei,
    const unsigned short* __restrict__ wsb,
    const float* __restrict__ gb1, const float* __restrict__ glng, const float* __restrict__ glnb,
    const float* __restrict__ pb2,
    const float* __restrict__ nmg, const float* __restrict__ nmb,
    const float* __restrict__ eb1,
    const float* __restrict__ elng, const float* __restrict__ elnb,
    const float* __restrict__ eW2, const float* __restrict__ eb2,
    float* __restrict__ out)
{
  __shared__ __align__(16) unsigned char TA[16384];   // counts / yT / ping / dots f32
  __shared__ __align__(16) unsigned char TB[16384];   // x0 / pong / final x
  __shared__ __align__(16) unsigned char sA[8192];    // feats -> A' -> exit scratch   (40 KB total)

  const int b = blockIdx.x, t = threadIdx.x;
  const int l = t & 63, w = t >> 6, lr = l & 15, lk = l >> 4;

  const unsigned short* wg1 = wsb;
  const unsigned short* wwc = wsb + 49152;
  const unsigned short* wp2 = wsb + 98304;
  const unsigned short* wem = wsb + 147456;
  const float*          bcf = (const float*)(wsb + 155648);
  const unsigned short* eT  = wsb + 156416;
  const unsigned*       tab = (const unsigned*)(wsb + 172800);

  // ---- setup: feats into sA, zero counts in TA ----
  if (t < NNODES) ((int*)sA)[t] = nf[b*NNODES + t];
  {
    u32x4 z = {0,0,0,0};
#pragma unroll
    for (int i=0;i<4;++i) *(u32x4*)(TA + t*64 + i*16) = z;   // 16 KB zeroed
  }
  __syncthreads();

  // x0 = emb[feat] -> TB + xreg ; edge histogram (2 edges/thread)
  u32x4 xr[4];
  {
    int n = t >> 2, q = t & 3;
    int f = ((const int*)sA)[n];
    const unsigned char* er = (const unsigned char*)(wem + f*HD) + q*64;
#pragma unroll
    for (int i=0;i<4;++i){
      u32x4 u = *(const u32x4*)(er + i*16);
      *(u32x4*)(TB + swz(n, q*64 + i*16)) = u;
      xr[i] = u;
    }
  }
  {
    int* cnts = (int*)TA;
#pragma unroll
    for (int e = t; e < NEDGE; e += 256){
      int sg = (ei[b*NEDGE + e]               - b*NNODES) & 63;
      int dg = (ei[NGRAPH*NEDGE + b*NEDGE + e] - b*NNODES) & 63;
      atomicAdd(&cnts[dg*64 + sg], 1);
    }
  }
  __syncthreads();

  // A' = A+I into sA (feats dead)
  buildA(TA, sA, t);
  __syncthreads();

  u32x4 wf[8];
#pragma unroll 1
  for (int i=0; i<3; ++i){
    // F1: load W1 frags (L2-hot); yT = (x@W1)^T : TB -> TA
    ldwg(wg1 + i*16384, t, wf);
    gemm_yT(TB, wf, TA, t);
    __syncthreads();
    // F2: h = A'@y + b1 : TA -> TB
    gemm_aggA(sA, TA, TB, gb1 + i*HD, t);
    __syncthreads();
    // F3: u = relu(LN(h)) : TB -> TA
    ln_rows<1>(TB, glng + i*HD, glnb + i*HD, TA, t);
    __syncthreads();
    // F4: load Wc frags; v = relu(u@Wc + bc) : TA -> TB
    ldwg(wwc + i*16384, t, wf);
    gemm_pp<1>(TA, TB, wf, bcf + i*HD, t);
    __syncthreads();
    // F5: load pW2 frags; h = v@pW2 + pb2 : TB -> TA
    ldwg(wp2 + i*16384, t, wf);
    gemm_pp<0>(TB, TA, wf, pb2 + i*HD, t);
    __syncthreads();
    // F6: x = LN(h [+xreg]) : TA -> TB + xreg
    if (i == 0) ln_resid<0>(TA, xr, nmg, nmb, TB, t);
    else        ln_resid<1>(TA, xr, nmg, nmb, TB, t);
    __syncthreads();
  }

  // exit-head scratch in sA (f32): part[256]@0, meansv[128]@256, m1p[256]@384, m1[128]@640
  float* part   = (float*)sA;
  float* meansv = (float*)sA + 256;
  float* m1p    = (float*)sA + 384;
  float* m1     = (float*)sA + 640;

  // ---- T1: dots MFMA (TB -> TA, bit4-XOR banked)  ||  column part-sums (TB -> sA) ----
  {
    f32x4 dacc[4] = {};
#pragma unroll
    for (int ks=0; ks<4; ++ks){
      int kByte = ks*64 + lk*16;
      bf16x8 af = asbf8(*(const u32x4*)(TB + swz(w*16 + lr, kByte)));
#pragma unroll
      for (int ct=0; ct<4; ++ct){
        bf16x8 bf = asbf8(*(const u32x4*)(TB + swz(ct*16 + lr, kByte)));
        dacc[ct] = MFMA(af, bf, dacc[ct], 0,0,0);
      }
    }
    float* dotsf = (float*)TA;
#pragma unroll
    for (int ct=0; ct<4; ++ct){
#pragma unroll
      for (int r=0; r<4; ++r){
        int row = w*16 + lk*4 + r;
        int col = (ct*16 + lr) ^ (((row>>2)&1)<<4);
        dotsf[row*64 + col] = dacc[ct][r] * 0.08838834764831843f;
      }
    }
  }
  {
    int c = t & 127, half = t >> 7;
    float s = 0.f;
#pragma unroll
    for (int r2=0; r2<32; ++r2){
      unsigned short u = *(const unsigned short*)(TB + swz(half*32 + r2, 2*c));
      s += __uint_as_float(((unsigned)u) << 16);
    }
    part[half*128 + c] = s;
  }
  __syncthreads();

  // ---- T2: meansv + triu table-extraction ----
  if (t < 128) meansv[t] = (part[t] + part[128 + t]) * (1.f/64.f);
  {
    const float* dotsf = (const float*)TA;
#pragma unroll
    for (int p = t; p < 2016; p += 256){
      unsigned ij = tab[p];
      int i = (int)(ij >> 16), j = (int)(ij & 0xffffu);
      int jc = j ^ (((i>>2)&1)<<4);
      out[(size_t)b*OSTRIDE + p] = dotsf[i*64 + jc];
    }
  }
  __syncthreads();

  // ---- T3: m1 = means @ eW1 + eb1, 2 lanes per output col (k-split halves) ----
  {
    int c = t & 127, half = t >> 7;
    const unsigned short* er = eT + c*128 + half*64;
    float s = 0.f;
#pragma unroll
    for (int kk=0; kk<8; ++kk){
      u32x4 u = *(const u32x4*)(er + kk*8);
      float f[8]; unpack8(u, f);
#pragma unroll
      for (int j=0;j<8;++j) s += meansv[half*64 + kk*8 + j] * f[j];
    }
    m1p[half*128 + c] = s;
  }
  __syncthreads();
  if (t < 128) m1[t] = m1p[t] + m1p[128 + t] + eb1[t];
  __syncthreads();

  // ---- T4: exit LN + final dot (wave 0) ----
  if (t < 64){
    float v0 = m1[t], v1 = m1[t+64];
    float s = v0 + v1, s2 = v0*v0 + v1*v1;
#pragma unroll
    for (int d=1; d<64; d<<=1){ s += __shfl_xor(s, d); s2 += __shfl_xor(s2, d); }
    float mu  = s * (1.f/128.f);
    float var = s2 * (1.f/128.f) - mu*mu;
    float rs  = rsqrtf(var + 1e-5f);
    float e0 = fmaxf((v0-mu)*rs*elng[t]    + elnb[t],    0.f);
    float e1 = fmaxf((v1-mu)*rs*elng[t+64] + elnb[t+64], 0.f);
    float pd = e0*eW2[t] + e1*eW2[t+64];
#pragma unroll
    for (int d=1; d<64; d<<=1) pd += __shfl_xor(pd, d);
    if (t == 0) out[(size_t)b*OSTRIDE + 2016] = pd + eb2[0];
  }
}

extern "C" void kernel_launch(void* const* d_in, const int* in_sizes, int n_in,
                              void* d_out, int out_size, void* d_ws, size_t ws_size,
                              hipStream_t stream)
{
  const int*   nf   = (const int*)d_in[0];
  const int*   ei   = (const int*)d_in[1];
  // d_in[2] = ptr (uniform 64-node graphs, unused)
  const float* emb  = (const float*)d_in[3];
  const float* gW1  = (const float*)d_in[4];
  const float* gb1  = (const float*)d_in[5];
  const float* glng = (const float*)d_in[6];
  const float* glnb = (const float*)d_in[7];
  const float* gW2  = (const float*)d_in[8];
  const float* gb2  = (const float*)d_in[9];
  const float* pW1  = (const float*)d_in[10];
  const float* pb1  = (const float*)d_in[11];
  const float* pW2  = (const float*)d_in[12];
  const float* pb2  = (const float*)d_in[13];
  const float* nmg  = (const float*)d_in[14];
  const float* nmb  = (const float*)d_in[15];
  const float* eW1  = (const float*)d_in[16];
  const float* eb1  = (const float*)d_in[17];
  const float* elng = (const float*)d_in[18];
  const float* elnb = (const float*)d_in[19];
  const float* eW2  = (const float*)d_in[20];
  const float* eb2  = (const float*)d_in[21];
  (void)in_sizes; (void)n_in; (void)out_size;

  if (ws_size < 176832u * sizeof(unsigned short)) return;
  unsigned short* wsb = (unsigned short*)d_ws;

  prep_wts<<<683, 256, 0, stream>>>(gW1, gW2, pW1, pW2, gb2, pb1, emb, eW1, wsb);
  gnn_fused<<<NGRAPH, 256, 0, stream>>>(nf, ei, wsb, gb1, glng, glnb, pb2,
                                        nmg, nmb, eb1, elng, elnb, eW2, eb2,
                                        (float*)d_out);
}

// Round 17
// 141.835 us; speedup vs baseline: 1.6800x; 1.6800x over previous
//
#include <hip/hip_runtime.h>
#include <hip/hip_bf16.h>

#define NGRAPH 2048
#define GRID 1024
#define NNODES 64
#define HD 128
#define NEDGE 512
#define OSTRIDE 2017

using bf16x8 = __attribute__((ext_vector_type(8))) __bf16;
using f32x4  = __attribute__((ext_vector_type(4))) float;
using u32x4  = __attribute__((ext_vector_type(4))) unsigned int;

// XOR swizzle for [64][128] bf16 tiles (256-B rows).
__device__ __forceinline__ int swz(int row, int cb){ return (row<<8) + (cb ^ ((row&7)<<4)); }

__device__ __forceinline__ unsigned short bf16r(float x){
  unsigned u = __float_as_uint(x);
  return (unsigned short)((u + 0x7fffu + ((u>>16)&1u)) >> 16);  // RNE (prep only)
}
// native cast: compiler emits v_cvt_*bf16* on gfx950 (guide m240: don't hand-write asm)
__device__ __forceinline__ unsigned short bf16c(float x){
  return __builtin_bit_cast(unsigned short, (__bf16)x);
}
__device__ __forceinline__ unsigned pack2c(float a, float b){
  return (unsigned)bf16c(a) | ((unsigned)bf16c(b) << 16);
}
__device__ __forceinline__ void unpack8(u32x4 u, float* f){
#pragma unroll
  for (int i=0;i<4;++i){
    unsigned w = u[i];
    f[2*i]   = __uint_as_float(w << 16);
    f[2*i+1] = __uint_as_float(w & 0xffff0000u);
  }
}
__device__ __forceinline__ bf16x8 asbf8(u32x4 u){ return __builtin_bit_cast(bf16x8, u); }
#define MFMA __builtin_amdgcn_mfma_f32_16x16x32_bf16

// ---- prep: PLAIN transposed bf16 [l][n][k] slabs; Wc = W2@pW1 merged; emb bf16;
// bc f32; eW1^T; triu table.
// ws (bf16 elems): w1 @0 (3x16384), wc @49152, pw2 @98304, emb @147456 (8192),
// bc f32[3][128] @155648 (768 slots), eW1T @156416 (16384), triuTab u32[2016] @172800.
__global__ void prep_wts(const float* __restrict__ g1, const float* __restrict__ g2,
                         const float* __restrict__ p1, const float* __restrict__ p2,
                         const float* __restrict__ b2, const float* __restrict__ pb1,
                         const float* __restrict__ emb, const float* __restrict__ eW1,
                         unsigned short* __restrict__ ws)
{
  int idx = blockIdx.x*256 + threadIdx.x;
  if (idx < 49152){            // W1^T plain
    int l = idx/16384, r = idx%16384, n = r>>7, k = r&127;
    ws[idx] = bf16r(g1[l*16384 + k*128 + n]);
  } else if (idx < 98304){     // Wc^T plain, Wc = W2 @ pW1 (f32 accumulate)
    int q = idx - 49152;
    int l = q/16384, r = q%16384, n = r>>7, k = r&127;
    const float* W2 = g2 + l*16384;
    const float* P1 = p1 + l*16384;
    float s = 0.f;
    for (int mm=0; mm<128; ++mm) s = fmaf(W2[k*128+mm], P1[mm*128+n], s);
    ws[idx] = bf16r(s);
  } else if (idx < 147456){    // pW2^T plain
    int q = idx - 98304;
    int l = q/16384, r = q%16384, n = r>>7, k = r&127;
    ws[idx] = bf16r(p2[l*16384 + k*128 + n]);
  } else if (idx < 155648){    // emb bf16
    ws[idx] = bf16r(emb[idx - 147456]);
  } else if (idx < 156032){    // bc[l][n] = b2[l]@pW1[l][:,n] + pb1[l][n]  (f32)
    int q = idx - 155648, l = q/128, n = q%128;
    const float* P1 = p1 + l*16384;
    const float* B2 = b2 + l*128;
    float s = pb1[l*128 + n];
    for (int mm=0; mm<128; ++mm) s = fmaf(B2[mm], P1[mm*128+n], s);
    ((float*)(ws + 155648))[q] = s;
  } else if (idx >= 156416 && idx < 172800){   // eW1^T bf16 [n][k]
    int q = idx - 156416, n = q>>7, k = q&127;
    ws[idx] = bf16r(eW1[k*128 + n]);
  } else if (idx >= 172800 && idx < 174816){   // triu (i,j) table
    int p = idx - 172800;
    float fi = (127.0f - sqrtf((float)(16129 - 8*p))) * 0.5f;
    int i = (int)fi;
    if (i > 62) i = 62;
    if (i < 0)  i = 0;
    while ((i+1)*(127-(i+1))/2 <= p) ++i;
    while (i*(127-i)/2 > p) --i;
    int j = i + 1 + (p - i*(127-i)/2);
    ((unsigned*)(ws + 172800))[p] = ((unsigned)i << 16) | (unsigned)j;
  }
}

// Direct-from-global weight frags (L2-hot): wave w's 4 B-frags for col-tile w.
__device__ __forceinline__ void ldwg(const unsigned short* wt, int t, u32x4* wf){
  const int l = t & 63, w = t >> 6, lr = l & 15, lk = l >> 4;
  const unsigned char* wb = (const unsigned char*)wt;
  int n = w*16 + lr;
#pragma unroll
  for (int ks=0; ks<4; ++ks)
    wf[ks] = *(const u32x4*)(wb + (n<<8) + ks*64 + lk*16);
}

// y = x @ W (wave w -> col-tile w), written TRANSPOSED (yT [feat][node], 128-B rows).
__device__ __forceinline__ void gemm_yT(const unsigned char* xs, const u32x4* wf,
                                        unsigned char* yT, int t)
{
  const int l = t & 63, w = t >> 6, lr = l & 15, lk = l >> 4;
  f32x4 acc[4] = {};
#pragma unroll
  for (int ks=0; ks<4; ++ks){
    int kByte = ks*64 + lk*16;
    bf16x8 bw = asbf8(wf[ks]);
#pragma unroll
    for (int rt=0; rt<4; ++rt){
      bf16x8 af = asbf8(*(const u32x4*)(xs + swz(rt*16 + lr, kByte)));
      acc[rt] = MFMA(af, bw, acc[rt], 0,0,0);
    }
  }
  int n = w*16 + lr;                          // output col = yT row
  int sw = (n & 7) << 4;
#pragma unroll
  for (int rt=0; rt<4; ++rt){
    unsigned w0 = pack2c(acc[rt][0], acc[rt][1]);
    unsigned w1 = pack2c(acc[rt][2], acc[rt][3]);
    int cb = (rt*32 + lk*8) ^ sw;
    *(unsigned long long*)(yT + (n<<7) + cb) = ((unsigned long long)w1 << 32) | w0;
  }
}

// Ping-pong 64x128 = in @ W + bias, optional relu. NO internal barrier.
template<int RELU>
__device__ __forceinline__ void gemm_pp(const unsigned char* in, unsigned char* outb,
                                        const u32x4* wf, const float* __restrict__ bias, int t)
{
  const int l = t & 63, w = t >> 6, lr = l & 15, lk = l >> 4;
  f32x4 acc[4] = {};
#pragma unroll
  for (int ks=0; ks<4; ++ks){
    int kByte = ks*64 + lk*16;
    bf16x8 bw = asbf8(wf[ks]);
#pragma unroll
    for (int rt=0; rt<4; ++rt){
      bf16x8 af = asbf8(*(const u32x4*)(in + swz(rt*16 + lr, kByte)));
      acc[rt] = MFMA(af, bw, acc[rt], 0,0,0);
    }
  }
  int c0 = w*16 + lr;
  float b0 = bias[c0];
  int cb0 = c0*2;
#pragma unroll
  for (int rt=0; rt<4; ++rt){
#pragma unroll
    for (int r=0; r<4; ++r){
      int row = rt*16 + lk*4 + r;
      float v0 = acc[rt][r] + b0;
      if (RELU) v0 = fmaxf(v0, 0.f);
      *(unsigned short*)(outb + swz(row, cb0)) = bf16c(v0);
    }
  }
}

// h = A' @ y + bias (A' in sA_; y as yT rows in yTt). Write std layout to outb.
__device__ __forceinline__ void gemm_aggA(const unsigned char* sA_, const unsigned char* yTt,
                                          unsigned char* outb, const float* __restrict__ bias, int t)
{
  const int l = t & 63, w = t >> 6, lr = l & 15, lk = l >> 4;
  f32x4 acc[4] = {};
  int n = w*16 + lr;                          // feat col (= yT row)
  int nsw = (n & 7) << 4;
#pragma unroll
  for (int ks=0; ks<2; ++ks){
    int kB = ks*64 + lk*16;
    bf16x8 bfr = asbf8(*(const u32x4*)(yTt + (n<<7) + (kB ^ nsw)));
#pragma unroll
    for (int rt=0; rt<4; ++rt){
      int m = rt*16 + lr;
      bf16x8 af = asbf8(*(const u32x4*)(sA_ + (m<<7) + (kB ^ ((m&7)<<4))));
      acc[rt] = MFMA(af, bfr, acc[rt], 0,0,0);
    }
  }
  float b0 = bias[n];
  int cb0 = n*2;
#pragma unroll
  for (int rt=0; rt<4; ++rt){
#pragma unroll
    for (int r=0; r<4; ++r){
      int row = rt*16 + lk*4 + r;
      *(unsigned short*)(outb + swz(row, cb0)) = bf16c(acc[rt][r] + b0);
    }
  }
}

// LayerNorm rows (512 thr: row t>>3, eighth t&7), out-of-place. Optional relu.
template<int RELU>
__device__ __forceinline__ void ln_rows(const unsigned char* inb,
                                        const float* __restrict__ g, const float* __restrict__ bb,
                                        unsigned char* outb, int t)
{
  int r = t >> 3, e = t & 7;
  int cb0 = e*32, c0 = e*16;
  float v[16];
#pragma unroll
  for (int i=0;i<2;++i){ u32x4 u = *(const u32x4*)(inb + swz(r, cb0 + i*16)); unpack8(u, v + i*8); }
  float s=0.f, s2=0.f;
#pragma unroll
  for (int i=0;i<16;++i){ s += v[i]; s2 += v[i]*v[i]; }
  s += __shfl_xor(s, 1); s2 += __shfl_xor(s2, 1);
  s += __shfl_xor(s, 2); s2 += __shfl_xor(s2, 2);
  s += __shfl_xor(s, 4); s2 += __shfl_xor(s2, 4);
  float mu  = s * (1.f/128.f);
  float var = s2 * (1.f/128.f) - mu*mu;
  float rs  = rsqrtf(var + 1e-5f);
#pragma unroll
  for (int i=0;i<4;++i){
    f32x4 gv = *(const f32x4*)(g + c0 + i*4);
    f32x4 bv = *(const f32x4*)(bb + c0 + i*4);
#pragma unroll
    for (int j=0;j<4;++j){
      float val = (v[i*4+j]-mu)*rs*gv[j] + bv[j];
      if (RELU) val = fmaxf(val, 0.f);
      v[i*4+j] = val;
    }
  }
#pragma unroll
  for (int i=0;i<2;++i){
    u32x4 u;
#pragma unroll
    for (int j=0;j<4;++j) u[j] = pack2c(v[i*8+2*j], v[i*8+2*j+1]);
    *(u32x4*)(outb + swz(r, cb0 + i*16)) = u;
  }
}

// Layer-end LN: x = LN(h [+ xreg]) -> outb AND xreg (residual slice kept in regs).
template<int RESID>
__device__ __forceinline__ void ln_resid(const unsigned char* inb, u32x4* xr,
                                         const float* __restrict__ g, const float* __restrict__ bb,
                                         unsigned char* outb, int t)
{
  int r = t >> 3, e = t & 7;
  int cb0 = e*32, c0 = e*16;
  float v[16];
#pragma unroll
  for (int i=0;i<2;++i){ u32x4 u = *(const u32x4*)(inb + swz(r, cb0 + i*16)); unpack8(u, v + i*8); }
  if constexpr (RESID){
    float x[16];
    unpack8(xr[0], x); unpack8(xr[1], x+8);
#pragma unroll
    for (int j=0;j<16;++j) v[j] += x[j];
  }
  float s=0.f, s2=0.f;
#pragma unroll
  for (int i=0;i<16;++i){ s += v[i]; s2 += v[i]*v[i]; }
  s += __shfl_xor(s, 1); s2 += __shfl_xor(s2, 1);
  s += __shfl_xor(s, 2); s2 += __shfl_xor(s2, 2);
  s += __shfl_xor(s, 4); s2 += __shfl_xor(s2, 4);
  float mu  = s * (1.f/128.f);
  float var = s2 * (1.f/128.f) - mu*mu;
  float rs  = rsqrtf(var + 1e-5f);
#pragma unroll
  for (int i=0;i<4;++i){
    f32x4 gv = *(const f32x4*)(g + c0 + i*4);
    f32x4 bv = *(const f32x4*)(bb + c0 + i*4);
#pragma unroll
    for (int j=0;j<4;++j) v[i*4+j] = (v[i*4+j]-mu)*rs*gv[j] + bv[j];
  }
#pragma unroll
  for (int i=0;i<2;++i){
    u32x4 u;
#pragma unroll
    for (int j=0;j<4;++j) u[j] = pack2c(v[i*8+2*j], v[i*8+2*j+1]);
    *(u32x4*)(outb + swz(r, cb0 + i*16)) = u;
    xr[i] = u;
  }
}

// Build A' = A+I bf16 [64][64] swizzled from int counts.
__device__ __forceinline__ void buildA(const unsigned char* cntb, unsigned char* sA_, int t){
  const int* cnts = (const int*)cntb;
  int n = t >> 3, c0 = (t & 7) * 8;
  float cv[8];
#pragma unroll
  for (int j=0;j<8;++j){
    int v = cnts[n*64 + c0 + j];
    if (c0 + j == n) v += 1;
    cv[j] = (float)v;
  }
  u32x4 u0;
#pragma unroll
  for (int j=0;j<4;++j) u0[j] = pack2c(cv[2*j], cv[2*j+1]);
  *(u32x4*)(sA_ + (n<<7) + ((c0*2) ^ ((n&7)<<4))) = u0;
}

// Dots + column part-sums for one graph (tile xb), dots -> dotb, part -> part.
__device__ __forceinline__ void dots_part(const unsigned char* xb, unsigned char* dotb,
                                          float* part, int t){
  const int l = t & 63, w = t >> 6, lr = l & 15, lk = l >> 4;
  {
    int a = w & 3, ch = w >> 2;
    f32x4 dacc[2] = {};
#pragma unroll
    for (int ks=0; ks<4; ++ks){
      int kByte = ks*64 + lk*16;
      bf16x8 af = asbf8(*(const u32x4*)(xb + swz(a*16 + lr, kByte)));
#pragma unroll
      for (int cc=0; cc<2; ++cc){
        int ct = ch*2 + cc;
        bf16x8 bf = asbf8(*(const u32x4*)(xb + swz(ct*16 + lr, kByte)));
        dacc[cc] = MFMA(af, bf, dacc[cc], 0,0,0);
      }
    }
    float* dotsf = (float*)dotb;
#pragma unroll
    for (int cc=0; cc<2; ++cc){
      int ct = ch*2 + cc;
#pragma unroll
      for (int r=0; r<4; ++r){
        int row = a*16 + lk*4 + r;
        int col = (ct*16 + lr) ^ (((row>>2)&1)<<4);
        dotsf[row*64 + col] = dacc[cc][r] * 0.08838834764831843f;
      }
    }
  }
  {
    int c = t & 127, q = t >> 7;
    float s = 0.f;
#pragma unroll
    for (int r2=0; r2<16; ++r2){
      unsigned short u = *(const unsigned short*)(xb + swz(q*16 + r2, 2*c));
      s += __uint_as_float(((unsigned)u) << 16);
    }
    part[q*128 + c] = s;
  }
}

__global__ __launch_bounds__(512, 2) void gnn_fused(
    const int* __restrict__ nf, const int* __restrict__ ei,
    const unsigned short* __restrict__ wsb,
    const float* __restrict__ gb1, const float* __restrict__ glng, const float* __restrict__ glnb,
    const float* __restrict__ pb2,
    const float* __restrict__ nmg, const float* __restrict__ nmb,
    const float* __restrict__ eb1,
    const float* __restrict__ elng, const float* __restrict__ elnb,
    const float* __restrict__ eW2, const float* __restrict__ eb2,
    float* __restrict__ out)
{
  __shared__ __align__(16) unsigned char TA0[16384], TB0[16384];
  __shared__ __align__(16) unsigned char TA1[16384], TB1[16384];
  __shared__ __align__(16) unsigned char sA0[8192], sA1[8192];   // 80 KB total

  const int b = blockIdx.x, t = threadIdx.x;
  const int g0 = 2*b, g1 = 2*b + 1;

  const unsigned short* wg1 = wsb;
  const unsigned short* wwc = wsb + 49152;
  const unsigned short* wp2 = wsb + 98304;
  const unsigned short* wem = wsb + 147456;
  const float*          bcf = (const float*)(wsb + 155648);
  const unsigned short* eT  = wsb + 156416;
  const unsigned*       tab = (const unsigned*)(wsb + 172800);

  u32x4 wfW1[4], wfWc[4], wfP2[4];
  ldwg(wg1, t, wfW1);            // issue layer-0 W1 at top; latency hides under setup

  // ---- setup: feats into sA0/sA1, zero counts in TA0/TA1 ----
  if (t < 64)       ((int*)sA0)[t]      = nf[g0*NNODES + t];
  else if (t < 128) ((int*)sA1)[t-64]   = nf[g1*NNODES + (t-64)];
  {
    u32x4 z = {0,0,0,0};
#pragma unroll
    for (int i=0;i<2;++i){
      *(u32x4*)(TA0 + t*32 + i*16) = z;
      *(u32x4*)(TA1 + t*32 + i*16) = z;
    }
  }
  __syncthreads();

  // x0 = emb[feat] -> TB + xreg (both graphs) ; edge histograms
  u32x4 xr0[2], xr1[2];
  {
    int n = t >> 3, e = t & 7;
    int f0 = ((const int*)sA0)[n];
    int f1 = ((const int*)sA1)[n];
    const unsigned char* e0 = (const unsigned char*)(wem + f0*HD) + e*32;
    const unsigned char* e1 = (const unsigned char*)(wem + f1*HD) + e*32;
#pragma unroll
    for (int i=0;i<2;++i){
      u32x4 u0 = *(const u32x4*)(e0 + i*16);
      u32x4 u1 = *(const u32x4*)(e1 + i*16);
      *(u32x4*)(TB0 + swz(n, e*32 + i*16)) = u0;
      *(u32x4*)(TB1 + swz(n, e*32 + i*16)) = u1;
      xr0[i] = u0; xr1[i] = u1;
    }
  }
  {
    int* c0 = (int*)TA0; int* c1 = (int*)TA1;
    int s0 = (ei[g0*NEDGE + t]               - g0*NNODES) & 63;
    int d0 = (ei[NGRAPH*NEDGE + g0*NEDGE + t] - g0*NNODES) & 63;
    atomicAdd(&c0[d0*64 + s0], 1);
    int s1 = (ei[g1*NEDGE + t]               - g1*NNODES) & 63;
    int d1 = (ei[NGRAPH*NEDGE + g1*NEDGE + t] - g1*NNODES) & 63;
    atomicAdd(&c1[d1*64 + s1], 1);
  }
  __syncthreads();

  // A' build for both graphs (feats in sA dead after x0 phase)
  buildA(TA0, sA0, t);
  buildA(TA1, sA1, t);
  __syncthreads();

#pragma unroll 1
  for (int i=0; i<3; ++i){
    // F1: issue Wc frags; yT = (x@W1)^T : TB -> TA (both)
    ldwg(wwc + i*16384, t, wfWc);
    gemm_yT(TB0, wfW1, TA0, t);
    gemm_yT(TB1, wfW1, TA1, t);
    __syncthreads();
    // F2: h = A'@y + b1 : TA -> TB (both)
    gemm_aggA(sA0, TA0, TB0, gb1 + i*HD, t);
    gemm_aggA(sA1, TA1, TB1, gb1 + i*HD, t);
    __syncthreads();
    // F3: issue pW2 frags; u = relu(LN(h)) : TB -> TA (both)
    ldwg(wp2 + i*16384, t, wfP2);
    ln_rows<1>(TB0, glng + i*HD, glnb + i*HD, TA0, t);
    ln_rows<1>(TB1, glng + i*HD, glnb + i*HD, TA1, t);
    __syncthreads();
    // F4: v = relu(u@Wc + bc) : TA -> TB (both)
    gemm_pp<1>(TA0, TB0, wfWc, bcf + i*HD, t);
    gemm_pp<1>(TA1, TB1, wfWc, bcf + i*HD, t);
    __syncthreads();
    // F5: issue next W1 frags; h = v@pW2 + pb2 : TB -> TA (both)
    if (i < 2) ldwg(wg1 + (i+1)*16384, t, wfW1);
    gemm_pp<0>(TB0, TA0, wfP2, pb2 + i*HD, t);
    gemm_pp<0>(TB1, TA1, wfP2, pb2 + i*HD, t);
    __syncthreads();
    // F6: x = LN(h [+xreg]) : TA -> TB + xreg (both)
    if (i == 0){
      ln_resid<0>(TA0, xr0, nmg, nmb, TB0, t);
      ln_resid<0>(TA1, xr1, nmg, nmb, TB1, t);
    } else {
      ln_resid<1>(TA0, xr0, nmg, nmb, TB0, t);
      ln_resid<1>(TA1, xr1, nmg, nmb, TB1, t);
    }
    __syncthreads();
  }

  // exit-head scratch (f32, per graph in its sA): part[512]@0, meansv[128]@512,
  // m1p[512]@640, m1[128]@1152
  float* part0 = (float*)sA0;            float* part1 = (float*)sA1;
  float* mv0   = (float*)sA0 + 512;      float* mv1   = (float*)sA1 + 512;
  float* m1p0  = (float*)sA0 + 640;      float* m1p1  = (float*)sA1 + 640;
  float* m10   = (float*)sA0 + 1152;     float* m11   = (float*)sA1 + 1152;

  // ---- T1: dots + part-sums (both graphs) ----
  dots_part(TB0, TA0, part0, t);
  dots_part(TB1, TA1, part1, t);
  __syncthreads();

  // ---- T2: meansv (split threads) + triu extraction (both) ----
  if (t < 128)      mv0[t]     = (part0[t]+part0[128+t]+part0[256+t]+part0[384+t]) * (1.f/64.f);
  else if (t < 256) mv1[t-128] = (part1[t-128]+part1[t]+part1[128+t]+part1[256+t]) * (1.f/64.f);
  {
    const float* d0 = (const float*)TA0;
    const float* d1 = (const float*)TA1;
#pragma unroll
    for (int p = t; p < 2016; p += 512){
      unsigned ij = tab[p];
      int i = (int)(ij >> 16), j = (int)(ij & 0xffffu);
      int jc = j ^ (((i>>2)&1)<<4);
      out[(size_t)g0*OSTRIDE + p] = d0[i*64 + jc];
      out[(size_t)g1*OSTRIDE + p] = d1[i*64 + jc];
    }
  }
  __syncthreads();

  // ---- T3: m1 = means @ eW1 + eb1 (both graphs) ----
  {
    int c = t & 127, q = t >> 7;
    const unsigned short* er = eT + c*128 + q*32;
    float s0 = 0.f, s1 = 0.f;
#pragma unroll
    for (int kk=0; kk<4; ++kk){
      u32x4 u = *(const u32x4*)(er + kk*8);
      float f[8]; unpack8(u, f);
#pragma unroll
      for (int j=0;j<8;++j){
        s0 += mv0[q*32 + kk*8 + j] * f[j];
        s1 += mv1[q*32 + kk*8 + j] * f[j];
      }
    }
    m1p0[q*128 + c] = s0;
    m1p1[q*128 + c] = s1;
  }
  __syncthreads();
  if (t < 128)      m10[t]     = m1p0[t]+m1p0[128+t]+m1p0[256+t]+m1p0[384+t] + eb1[t];
  else if (t < 256) m11[t-128] = m1p1[t-128]+m1p1[t]+m1p1[128+t]+m1p1[256+t] + eb1[t-128];
  __syncthreads();

  // ---- T4: exit LN + final dot (wave 0 -> g0, wave 1 -> g1) ----
  if (t < 128){
    int lane = t & 63;
    const float* m1g = (t < 64) ? m10 : m11;
    int gg = (t < 64) ? g0 : g1;
    float v0 = m1g[lane], v1 = m1g[lane+64];
    float s = v0 + v1, s2 = v0*v0 + v1*v1;
#pragma unroll
    for (int d=1; d<64; d<<=1){ s += __shfl_xor(s, d); s2 += __shfl_xor(s2, d); }
    float mu  = s * (1.f/128.f);
    float var = s2 * (1.f/128.f) - mu*mu;
    float rs  = rsqrtf(var + 1e-5f);
    float e0 = fmaxf((v0-mu)*rs*elng[lane]    + elnb[lane],    0.f);
    float e1 = fmaxf((v1-mu)*rs*elng[lane+64] + elnb[lane+64], 0.f);
    float pd = e0*eW2[lane] + e1*eW2[lane+64];
#pragma unroll
    for (int d=1; d<64; d<<=1) pd += __shfl_xor(pd, d);
    if (lane == 0) out[(size_t)gg*OSTRIDE + 2016] = pd + eb2[0];
  }
}

extern "C" void kernel_launch(void* const* d_in, const int* in_sizes, int n_in,
                              void* d_out, int out_size, void* d_ws, size_t ws_size,
                              hipStream_t stream)
{
  const int*   nf   = (const int*)d_in[0];
  const int*   ei   = (const int*)d_in[1];
  // d_in[2] = ptr (uniform 64-node graphs, unused)
  const float* emb  = (const float*)d_in[3];
  const float* gW1  = (const float*)d_in[4];
  const float* gb1  = (const float*)d_in[5];
  const float* glng = (const float*)d_in[6];
  const float* glnb = (const float*)d_in[7];
  const float* gW2  = (const float*)d_in[8];
  const float* gb2  = (const float*)d_in[9];
  const float* pW1  = (const float*)d_in[10];
  const float* pb1  = (const float*)d_in[11];
  const float* pW2  = (const float*)d_in[12];
  const float* pb2  = (const float*)d_in[13];
  const float* nmg  = (const float*)d_in[14];
  const float* nmb  = (const float*)d_in[15];
  const float* eW1  = (const float*)d_in[16];
  const float* eb1  = (const float*)d_in[17];
  const float* elng = (const float*)d_in[18];
  const float* elnb = (const float*)d_in[19];
  const float* eW2  = (const float*)d_in[20];
  const float* eb2  = (const float*)d_in[21];
  (void)in_sizes; (void)n_in; (void)out_size;

  if (ws_size < 176832u * sizeof(unsigned short)) return;
  unsigned short* wsb = (unsigned short*)d_ws;

  prep_wts<<<683, 256, 0, stream>>>(gW1, gW2, pW1, pW2, gb2, pb1, emb, eW1, wsb);
  gnn_fused<<<GRID, 512, 0, stream>>>(nf, ei, wsb, gb1, glng, glnb, pb2,
                                      nmg, nmb, eb1, elng, elnb, eW2, eb2,
                                      (float*)d_out);
}